// Round 7
// baseline (608.308 us; speedup 1.0000x reference)
//
#include <hip/hip_runtime.h>
#include <cstdint>
#include <cstddef>

#define BATCH 8
#define SEQ   2048
#define DM    1024
#define DE    2048   // D_MODEL*EXPAND
#define DSZ   256    // D_STATE
#define MROWS (BATCH*SEQ)  // 16384
#define MCHUNK 8192        // M rows per chunk (2 chunks)

typedef _Float16 f16;
typedef _Float16 f16x4 __attribute__((ext_vector_type(4)));
typedef _Float16 f16x8 __attribute__((ext_vector_type(8)));
typedef float  f32x4  __attribute__((ext_vector_type(4)));

// async global->LDS, 16B per lane (global_load_lds_dwordx4).
__device__ __forceinline__ void glds16(const void* gp, void* lp) {
  __builtin_amdgcn_global_load_lds(
      (const __attribute__((address_space(1))) void*)gp,
      (__attribute__((address_space(3))) void*)lp, 16, 0, 0);
}

__device__ __forceinline__ float silu_f(float x) {
  return x * __builtin_amdgcn_rcpf(1.0f + __expf(-x));
}

// LDS XOR-swizzle: 16B-chunk k8 within a 64B row is permuted by ((row>>1)&3)
// so fragment reads are 2-way-per-bank-group (free) instead of 8-way.
__device__ __forceinline__ int swz(int k8, int r) { return k8 ^ ((r >> 1) & 3); }

// ---------------- split fp32 -> hi/lo f16 (vectorized) ----------------
__global__ void split_x_k(const float* __restrict__ in, f16* __restrict__ oh,
                          f16* __restrict__ ol, int n) {
  int i = (blockIdx.x * blockDim.x + threadIdx.x) * 4;
  const int stride = gridDim.x * blockDim.x * 4;
  for (; i < n; i += stride) {
    float4 v = *(const float4*)(in + i);
    f16x4 h, l;
    h[0] = (f16)v.x; l[0] = (f16)(v.x - (float)h[0]);
    h[1] = (f16)v.y; l[1] = (f16)(v.y - (float)h[1]);
    h[2] = (f16)v.z; l[2] = (f16)(v.z - (float)h[2]);
    h[3] = (f16)v.w; l[3] = (f16)(v.w - (float)h[3]);
    *(f16x4*)(oh + i) = h;
    *(f16x4*)(ol + i) = l;
  }
}

// ---------------- transpose + split: in[R][C] fp32 -> hi/lo [C][R] f16 ----------------
__global__ void transpose_split_k(const float* __restrict__ in, f16* __restrict__ oh,
                                  f16* __restrict__ ol, int R, int C) {
  __shared__ float tile[32][33];
  const int c0 = blockIdx.x * 32, r0 = blockIdx.y * 32;
  const int tx = threadIdx.x, ty = threadIdx.y; // 32 x 8
  #pragma unroll
  for (int i = 0; i < 4; ++i)
    tile[ty + i*8][tx] = in[(size_t)(r0 + ty + i*8) * C + c0 + tx];
  __syncthreads();
  #pragma unroll
  for (int i = 0; i < 4; ++i) {
    float v = tile[tx][ty + i*8];
    f16 h = (f16)v;
    size_t idx = (size_t)(c0 + ty + i*8) * R + r0 + tx;
    oh[idx] = h;
    ol[idx] = (f16)(v - (float)h);
  }
}

// ---------------- transpose + cast to f16 ----------------
__global__ void transpose_cast_f16_k(const float* __restrict__ in, f16* __restrict__ out, int R, int C) {
  __shared__ float tile[32][33];
  const int c0 = blockIdx.x * 32, r0 = blockIdx.y * 32;
  const int tx = threadIdx.x, ty = threadIdx.y;
  #pragma unroll
  for (int i = 0; i < 4; ++i)
    tile[ty + i*8][tx] = in[(size_t)(r0 + ty + i*8) * C + c0 + tx];
  __syncthreads();
  #pragma unroll
  for (int i = 0; i < 4; ++i)
    out[(size_t)(c0 + ty + i*8) * R + r0 + tx] = (f16)tile[tx][ty + i*8];
}

// ---------------- GEMM1: xproj = silu(x @ W_in + b), hi/lo concat-K, 8-phase ----------------
// m201-style template: 256x256 tile, 512 thr / 8 waves (2Mx4N), wave tile 128x64,
// BK=64 (two proven 32-k swizzled sub-layouts), LDS 128KB dbuf, 1 block/CU.
// Virtual K=3072 (seg0 Ah*Bh, seg1 Ah*Bl, seg2 Al*Bh), 48 K-tiles, 4 phases each:
// {stage 2 glds(kt+1) ; vmcnt(6) at ph0/ph2 ; s_barrier ; ds_read subtile ;
//  setprio(1) 16xMFMA setprio(0) ; s_barrier}. vmcnt never drains to 0 in-loop.
__global__ __launch_bounds__(512, 2) void gemm1_k(const f16* __restrict__ Ah, const f16* __restrict__ Al,
                                                  const f16* __restrict__ Bh, const f16* __restrict__ Bl,
                                                  const float* __restrict__ bias,
                                                  f16* __restrict__ Ch, f16* __restrict__ Cl) {
  const int K = 1024, N = 2048;
  __shared__ f16 sA[2][2][8192];  // [slot][sub][256 rows x 32 k] = 64KB
  __shared__ f16 sB[2][2][8192];  // 64KB

  const int tid = threadIdx.x;
  const int w = tid >> 6, l = tid & 63;
  const int bid = blockIdx.x;              // 0..255
  const int xcd = bid & 7, loc = bid >> 3; // loc 0..31
  const int mt = xcd * 4 + (loc & 3);      // 0..31
  const int nt = loc >> 2;                 // 0..7
  const int bm = mt * 256, bn = nt * 256;
  const int wm = (w >> 2) * 128, wn = (w & 3) * 64;
  const int lr = l & 15, lq = l >> 4;

  // staging: per sub-tile per tensor 1024 16B-chunks; thread owns chunks tid and 512+tid.
  const int rA0 = tid >> 2,        k8A0 = swz(tid & 3, rA0);
  const int rA1 = 128 + (tid >> 2), k8A1 = swz(tid & 3, rA1);
  const size_t baseA0 = (size_t)(bm + rA0) * K + k8A0 * 8;
  const size_t baseA1 = (size_t)(bm + rA1) * K + k8A1 * 8;
  const size_t baseB0 = (size_t)(bn + rA0) * K + k8A0 * 8;
  const size_t baseB1 = (size_t)(bn + rA1) * K + k8A1 * 8;
  const int dst0 = tid * 8, dst1 = (512 + tid) * 8;

  // stage sub s of K-tile t (2 glds each)
  auto stageA = [&](int t, int s) {
    const int seg = t >> 4;
    const int koff = (t & 15) * 64 + s * 32;
    const f16* src = (seg < 2 ? Ah : Al);
    f16* d = &sA[t & 1][s][0];
    glds16(src + baseA0 + koff, d + dst0);
    glds16(src + baseA1 + koff, d + dst1);
  };
  auto stageB = [&](int t, int s) {
    const int seg = t >> 4;
    const int koff = (t & 15) * 64 + s * 32;
    const f16* src = (seg == 1 ? Bl : Bh);
    f16* d = &sB[t & 1][s][0];
    glds16(src + baseB0 + koff, d + dst0);
    glds16(src + baseB1 + koff, d + dst1);
  };

  // fragment read offsets within a sub-layout [256][32]
  int offA[8], offB[4];
  #pragma unroll
  for (int i = 0; i < 8; ++i) {
    const int row = wm + i*16 + lr;
    offA[i] = row * 32 + swz(lq, row) * 8;
  }
  #pragma unroll
  for (int j = 0; j < 4; ++j) {
    const int row = wn + j*16 + lr;
    offB[j] = row * 32 + swz(lq, row) * 8;
  }

  f32x4 acc[8][4] = {};

  // prologue: stage tile 0 fully, drain once
  stageA(0, 0); stageB(0, 0); stageA(0, 1); stageB(0, 1);
  __syncthreads();  // full vmcnt drain (once)

  for (int kt = 0; kt < 48; ++kt) {
    const int slot = kt & 1;
    const f16* bA0 = &sA[slot][0][0];
    const f16* bA1 = &sA[slot][1][0];
    const f16* bB0 = &sB[slot][0][0];
    const f16* bB1 = &sB[slot][1][0];
    f16x8 a[4], bf[4];

    // ---- phase 0: sub0, M-half0 ----
    if (kt < 47) { stageA(kt + 1, 0); asm volatile("s_waitcnt vmcnt(6)" ::: "memory"); }
    else         {                    asm volatile("s_waitcnt vmcnt(4)" ::: "memory"); }
    __builtin_amdgcn_s_barrier();
    asm volatile("" ::: "memory");
    #pragma unroll
    for (int j = 0; j < 4; ++j) bf[j] = *(const f16x8*)(bB0 + offB[j]);
    #pragma unroll
    for (int i = 0; i < 4; ++i) a[i] = *(const f16x8*)(bA0 + offA[i]);
    __builtin_amdgcn_s_setprio(1);
    #pragma unroll
    for (int i = 0; i < 4; ++i)
      #pragma unroll
      for (int j = 0; j < 4; ++j)
        acc[i][j] = __builtin_amdgcn_mfma_f32_16x16x32_f16(a[i], bf[j], acc[i][j], 0, 0, 0);
    __builtin_amdgcn_s_setprio(0);
    asm volatile("" ::: "memory");
    __builtin_amdgcn_s_barrier();

    // ---- phase 1: sub0, M-half1 (reuse bf) ----
    if (kt < 47) stageB(kt + 1, 0);
    __builtin_amdgcn_s_barrier();
    asm volatile("" ::: "memory");
    #pragma unroll
    for (int i = 0; i < 4; ++i) a[i] = *(const f16x8*)(bA0 + offA[4 + i]);
    __builtin_amdgcn_s_setprio(1);
    #pragma unroll
    for (int i = 0; i < 4; ++i)
      #pragma unroll
      for (int j = 0; j < 4; ++j)
        acc[4 + i][j] = __builtin_amdgcn_mfma_f32_16x16x32_f16(a[i], bf[j], acc[4 + i][j], 0, 0, 0);
    __builtin_amdgcn_s_setprio(0);
    asm volatile("" ::: "memory");
    __builtin_amdgcn_s_barrier();

    // ---- phase 2: sub1, M-half0 ----
    if (kt < 47) { stageA(kt + 1, 1); asm volatile("s_waitcnt vmcnt(6)" ::: "memory"); }
    else         {                    asm volatile("s_waitcnt vmcnt(0)" ::: "memory"); }
    __builtin_amdgcn_s_barrier();
    asm volatile("" ::: "memory");
    #pragma unroll
    for (int j = 0; j < 4; ++j) bf[j] = *(const f16x8*)(bB1 + offB[j]);
    #pragma unroll
    for (int i = 0; i < 4; ++i) a[i] = *(const f16x8*)(bA1 + offA[i]);
    __builtin_amdgcn_s_setprio(1);
    #pragma unroll
    for (int i = 0; i < 4; ++i)
      #pragma unroll
      for (int j = 0; j < 4; ++j)
        acc[i][j] = __builtin_amdgcn_mfma_f32_16x16x32_f16(a[i], bf[j], acc[i][j], 0, 0, 0);
    __builtin_amdgcn_s_setprio(0);
    asm volatile("" ::: "memory");
    __builtin_amdgcn_s_barrier();

    // ---- phase 3: sub1, M-half1 (reuse bf) ----
    if (kt < 47) stageB(kt + 1, 1);
    __builtin_amdgcn_s_barrier();
    asm volatile("" ::: "memory");
    #pragma unroll
    for (int i = 0; i < 4; ++i) a[i] = *(const f16x8*)(bA1 + offA[4 + i]);
    __builtin_amdgcn_s_setprio(1);
    #pragma unroll
    for (int i = 0; i < 4; ++i)
      #pragma unroll
      for (int j = 0; j < 4; ++j)
        acc[4 + i][j] = __builtin_amdgcn_mfma_f32_16x16x32_f16(a[i], bf[j], acc[4 + i][j], 0, 0, 0);
    __builtin_amdgcn_s_setprio(0);
    asm volatile("" ::: "memory");
    __builtin_amdgcn_s_barrier();
  }

  // epilogue: C/D layout col = lane&15, row = (lane>>4)*4 + reg
  #pragma unroll
  for (int j = 0; j < 4; ++j) {
    const int col = bn + wn + j*16 + lr;
    const float bv = bias[col];
    #pragma unroll
    for (int i = 0; i < 8; ++i)
      #pragma unroll
      for (int r4 = 0; r4 < 4; ++r4) {
        const int row = bm + wm + i*16 + lq*4 + r4;
        const float s = silu_f(acc[i][j][r4] + bv);
        const f16 h = (f16)s;
        const size_t idx = (size_t)row * N + col;
        Ch[idx] = h;
        Cl[idx] = (f16)(s - (float)h);
      }
  }
}

// ---------------- GEMM2: upd = xproj @ W_state + b -> fp32 ----------------
// 256 threads, 4 waves, block tile 64x64, wave tile 32x32. K=2048, N=256.
// BK=64 as TWO proven 32-k sub-tiles per K-step: 24 MFMA per barrier,
// same zero-conflict LDS layout per sub-tile. 2-phase dbuf, one barrier/K-step.
// 1D grid 512, XCD-grouped.  [round-6 verbatim]
__global__ __launch_bounds__(256) void gemm2s_k(const f16* __restrict__ Ah, const f16* __restrict__ Al,
                                                const f16* __restrict__ Bh, const f16* __restrict__ Bl,
                                                const float* __restrict__ bias,
                                                float* __restrict__ C) {
  const int K = 2048, N = 256;
  __shared__ f16 sAh[2][2][2048], sAl[2][2][2048], sBh[2][2][2048], sBl[2][2][2048];

  const int tid = threadIdx.x;
  const int w = tid >> 6, l = tid & 63;
  const int bid = blockIdx.x;           // 0..511
  const int bm = (bid & 127) * 64;
  const int bn = (bid >> 7) * 64;
  const int wm = (w & 1) * 32, wn = (w >> 1) * 32;
  const int lr = l & 15, lq = l >> 4;

  const int r = tid >> 2, k8 = swz(tid & 3, r);
  const f16* pAh = Ah + (size_t)(bm + r) * K + k8 * 8;
  const f16* pAl = Al + (size_t)(bm + r) * K + k8 * 8;
  const f16* pBh = Bh + (size_t)(bn + r) * K + k8 * 8;
  const f16* pBl = Bl + (size_t)(bn + r) * K + k8 * 8;
  const int dst = tid * 8;

  int offA[2], offB[2];
  #pragma unroll
  for (int i = 0; i < 2; ++i) {
    const int row = wm + i*16 + lr;
    offA[i] = row * 32 + swz(lq, row) * 8;
  }
  #pragma unroll
  for (int j = 0; j < 2; ++j) {
    const int row = wn + j*16 + lr;
    offB[j] = row * 32 + swz(lq, row) * 8;
  }

  f32x4 acc[2][2] = {};

  glds16(pAh,      &sAh[0][0][dst]); glds16(pAh + 32, &sAh[0][1][dst]);
  glds16(pAl,      &sAl[0][0][dst]); glds16(pAl + 32, &sAl[0][1][dst]);
  glds16(pBh,      &sBh[0][0][dst]); glds16(pBh + 32, &sBh[0][1][dst]);
  glds16(pBl,      &sBl[0][0][dst]); glds16(pBl + 32, &sBl[0][1][dst]);
  pAh += 64; pAl += 64; pBh += 64; pBl += 64;
  __syncthreads();

  for (int kt = 0; kt < 32; ++kt) {   // 32 K-steps of 64
    const int cur = kt & 1;
    if (kt < 31) {
      const int nxt = cur ^ 1;
      glds16(pAh,      &sAh[nxt][0][dst]); glds16(pAh + 32, &sAh[nxt][1][dst]);
      glds16(pAl,      &sAl[nxt][0][dst]); glds16(pAl + 32, &sAl[nxt][1][dst]);
      glds16(pBh,      &sBh[nxt][0][dst]); glds16(pBh + 32, &sBh[nxt][1][dst]);
      glds16(pBl,      &sBl[nxt][0][dst]); glds16(pBl + 32, &sBl[nxt][1][dst]);
      pAh += 64; pAl += 64; pBh += 64; pBl += 64;
    }
    #pragma unroll
    for (int s = 0; s < 2; ++s) {
      f16x8 ah[2], al[2], bh[2], bl[2];
      #pragma unroll
      for (int i = 0; i < 2; ++i) {
        ah[i] = *(const f16x8*)(&sAh[cur][s][0] + offA[i]);
        al[i] = *(const f16x8*)(&sAl[cur][s][0] + offA[i]);
      }
      #pragma unroll
      for (int j = 0; j < 2; ++j) {
        bh[j] = *(const f16x8*)(&sBh[cur][s][0] + offB[j]);
        bl[j] = *(const f16x8*)(&sBl[cur][s][0] + offB[j]);
      }
      __builtin_amdgcn_s_setprio(1);
      #pragma unroll
      for (int i = 0; i < 2; ++i)
        #pragma unroll
        for (int j = 0; j < 2; ++j) {
          acc[i][j] = __builtin_amdgcn_mfma_f32_16x16x32_f16(ah[i], bh[j], acc[i][j], 0, 0, 0);
          acc[i][j] = __builtin_amdgcn_mfma_f32_16x16x32_f16(ah[i], bl[j], acc[i][j], 0, 0, 0);
          acc[i][j] = __builtin_amdgcn_mfma_f32_16x16x32_f16(al[i], bh[j], acc[i][j], 0, 0, 0);
        }
      __builtin_amdgcn_s_setprio(0);
    }
    __syncthreads();
  }

  #pragma unroll
  for (int j = 0; j < 2; ++j) {
    const int col = bn + wn + j*16 + lr;
    const float bv = bias[col];
    #pragma unroll
    for (int i = 0; i < 2; ++i)
      #pragma unroll
      for (int r4 = 0; r4 < 4; ++r4) {
        const int row = bm + wm + i*16 + lq*4 + r4;
        C[(size_t)row * N + col] = acc[i][j][r4] + bv;
      }
  }
}

// ---------------- GEMM3: out = states @ W_out + b -> fp32 (single f16) ----------------
// T3-minimum 2-phase double-buffer, one barrier per K-tile.  [round-4 verbatim]
__global__ __launch_bounds__(256) void gemm3_k(const f16* __restrict__ A,
                                               const f16* __restrict__ Bt,
                                               const float* __restrict__ bias,
                                               float* __restrict__ C) {
  const int K = 256, N = 1024;
  __shared__ f16 sA[2][4096], sB[2][4096];  // 32KB

  const int tid = threadIdx.x;
  const int w = tid >> 6, l = tid & 63;
  const int bm = blockIdx.y * 128, bn = blockIdx.x * 128;
  const int wm = (w >> 1) * 64, wn = (w & 1) * 64;
  const int lr = l & 15, lq = l >> 4;

  const f16 *pA[2], *pB[2]; int dstc[2];
  #pragma unroll
  for (int p = 0; p < 2; ++p) {
    const int c = p * 256 + tid;
    const int r = c >> 2, k8 = swz(c & 3, r);
    pA[p] = A  + (size_t)(bm + r) * K + k8 * 8;
    pB[p] = Bt + (size_t)(bn + r) * K + k8 * 8;
    dstc[p] = c * 8;
  }

  int offA[4], offB[4];
  #pragma unroll
  for (int i = 0; i < 4; ++i) {
    const int rowA = wm + i*16 + lr;
    const int rowB = wn + i*16 + lr;
    offA[i] = rowA * 32 + swz(lq, rowA) * 8;
    offB[i] = rowB * 32 + swz(lq, rowB) * 8;
  }

  f32x4 acc[4][4] = {};

  glds16(pA[0], &sA[0][dstc[0]]); glds16(pA[1], &sA[0][dstc[1]]);
  glds16(pB[0], &sB[0][dstc[0]]); glds16(pB[1], &sB[0][dstc[1]]);
  pA[0] += 32; pA[1] += 32; pB[0] += 32; pB[1] += 32;
  __syncthreads();

  for (int kt = 0; kt < 8; ++kt) {
    const int cur = kt & 1;
    if (kt < 7) {
      const int nxt = cur ^ 1;
      glds16(pA[0], &sA[nxt][dstc[0]]); glds16(pA[1], &sA[nxt][dstc[1]]);
      glds16(pB[0], &sB[nxt][dstc[0]]); glds16(pB[1], &sB[nxt][dstc[1]]);
      pA[0] += 32; pA[1] += 32; pB[0] += 32; pB[1] += 32;
    }
    f16x8 af[4], bfr[4];
    #pragma unroll
    for (int i = 0; i < 4; ++i) af[i]  = *(const f16x8*)(&sA[cur][0] + offA[i]);
    #pragma unroll
    for (int j = 0; j < 4; ++j) bfr[j] = *(const f16x8*)(&sB[cur][0] + offB[j]);
    __builtin_amdgcn_s_setprio(1);
    #pragma unroll
    for (int i = 0; i < 4; ++i)
      #pragma unroll
      for (int j = 0; j < 4; ++j)
        acc[i][j] = __builtin_amdgcn_mfma_f32_16x16x32_f16(af[i], bfr[j], acc[i][j], 0, 0, 0);
    __builtin_amdgcn_s_setprio(0);
    __syncthreads();
  }

  #pragma unroll
  for (int j = 0; j < 4; ++j) {
    const int col = bn + wn + j*16 + lr;
    const float bv = bias[col];
    #pragma unroll
    for (int i = 0; i < 4; ++i)
      #pragma unroll
      for (int r4 = 0; r4 < 4; ++r4) {
        const int row = bm + wm + i*16 + lq*4 + r4;
        C[(size_t)row * N + col] = acc[i][j][r4] + bv;
      }
  }
}

// ---------------- sequential scan: state = silu(state + u_t), fp32 -> f16 states ----------------
// 32 blocks x 64 threads; 3-buffer rotation = loads issued 32 steps ahead.
#define L2E 1.4426950408889634f
__global__ __launch_bounds__(64) void scan_k(const float* __restrict__ upd,
                                             const float* __restrict__ init,
                                             f16* __restrict__ states) {
  const int b = blockIdx.x >> 2, sq = blockIdx.x & 3;
  const int s = sq * 64 + threadIdx.x;
  const float* u = upd + (size_t)b * SEQ * DSZ + s;
  f16* st = states + (size_t)b * SEQ * DSZ + s;
  float state = init[s];

  float r0[16], r1[16], r2[16], ulog[16];
  #pragma unroll
  for (int i = 0; i < 16; ++i) r0[i] = u[(size_t)i * DSZ];
  #pragma unroll
  for (int i = 0; i < 16; ++i) r1[i] = u[(size_t)(16 + i) * DSZ];
  #pragma unroll
  for (int i = 0; i < 16; ++i) ulog[i] = r0[i] * (-L2E);

  for (int t0 = 0; t0 < SEQ; t0 += 16) {
    // loads for t0+32 (two blocks ahead, off the dependency chain)
    if (t0 + 32 < SEQ) {
      #pragma unroll
      for (int i = 0; i < 16; ++i) r2[i] = u[(size_t)(t0 + 32 + i) * DSZ];
    }
    // pure-register dependent chain
    f16 res[16];
    #pragma unroll
    for (int i = 0; i < 16; ++i) {
      const float e = __builtin_amdgcn_exp2f(__builtin_fmaf(state, -L2E, ulog[i]));
      const float x = state + r0[i];
      state = x * __builtin_amdgcn_rcpf(1.0f + e);
      res[i] = (f16)state;
    }
    // stores (off-chain)
    #pragma unroll
    for (int i = 0; i < 16; ++i) st[(size_t)(t0 + i) * DSZ] = res[i];
    // rotate buffers
    #pragma unroll
    for (int i = 0; i < 16; ++i) { r0[i] = r1[i]; ulog[i] = r1[i] * (-L2E); r1[i] = r2[i]; }
  }
}

extern "C" void kernel_launch(void* const* d_in, const int* in_sizes, int n_in,
                              void* d_out, int out_size, void* d_ws, size_t ws_size,
                              hipStream_t stream) {
  const float* x       = (const float*)d_in[0];
  const float* W_in    = (const float*)d_in[1];
  const float* b_in    = (const float*)d_in[2];
  const float* W_state = (const float*)d_in[3];
  const float* b_state = (const float*)d_in[4];
  const float* W_out   = (const float*)d_in[5];
  const float* b_out   = (const float*)d_in[6];
  const float* init_st = (const float*)d_in[7];
  float* out = (float*)d_out;

  char* ws = (char*)d_ws;
  f16*   xh        = (f16*)(ws + 0);             // 32MB [16384][1024]
  f16*   xl        = (f16*)(ws + 33554432);      // 32MB
  f16*   xproj_h   = (f16*)(ws + 67108864);      // 32MB [8192][2048] (per chunk)
  f16*   xproj_l   = (f16*)(ws + 100663296);     // 32MB
  float* upd       = (float*)(ws + 134217728);   // 16MB [16384][256] fp32
  f16*   states    = (f16*)(ws + 150994944);     // 8MB  [16384][256]
  f16*   w_in_h    = (f16*)(ws + 159383552);     // 4MB  [2048][1024]
  f16*   w_in_l    = (f16*)(ws + 163577856);     // 4MB
  f16*   w_state_h = (f16*)(ws + 167772160);     // 1MB  [256][2048]
  f16*   w_state_l = (f16*)(ws + 168820736);     // 1MB
  f16*   w_out_t   = (f16*)(ws + 169869312);     // 0.5MB [1024][256]  (end = 170,393,600 B)

  // 1) pre-split x, transpose+split weights
  split_x_k<<<4096, 256, 0, stream>>>(x, xh, xl, MROWS * DM);
  dim3 tb(32, 8);
  transpose_split_k<<<dim3(DE/32,  DM/32), tb, 0, stream>>>(W_in,    w_in_h,    w_in_l,    DM,  DE);
  transpose_split_k<<<dim3(DSZ/32, DE/32), tb, 0, stream>>>(W_state, w_state_h, w_state_l, DE,  DSZ);
  transpose_cast_f16_k<<<dim3(DM/32, DSZ/32), tb, 0, stream>>>(W_out, w_out_t, DSZ, DM);

  // 2/3) chunked: xproj = silu(x@W_in+b) -> hi/lo f16; upd = xproj@W_state+b -> fp32
  for (int c = 0; c < 2; ++c) {
    const size_t ro = (size_t)c * MCHUNK;
    gemm1_k<<<256, 512, 0, stream>>>(
        xh + ro * DM, xl + ro * DM, w_in_h, w_in_l, b_in, xproj_h, xproj_l);
    gemm2s_k<<<512, 256, 0, stream>>>(
        xproj_h, xproj_l, w_state_h, w_state_l, b_state, upd + ro * DSZ);
  }

  // 4) sequential scan (fp32), states as f16
  scan_k<<<BATCH*4, 64, 0, stream>>>(upd, init_st, states);

  // 5) out = states @ W_out + b_out -> fp32
  gemm3_k<<<dim3(DM/128, MROWS/128), 256, 0, stream>>>(states, w_out_t, b_out, out);
}

// Round 8
// 531.225 us; speedup vs baseline: 1.1451x; 1.1451x over previous
//
#include <hip/hip_runtime.h>
#include <cstdint>
#include <cstddef>

#define BATCH 8
#define SEQ   2048
#define DM    1024
#define DE    2048   // D_MODEL*EXPAND
#define DSZ   256    // D_STATE
#define MROWS (BATCH*SEQ)  // 16384
#define MCHUNK 8192        // M rows per chunk (2 chunks)

typedef _Float16 f16;
typedef _Float16 f16x4 __attribute__((ext_vector_type(4)));
typedef _Float16 f16x8 __attribute__((ext_vector_type(8)));
typedef float  f32x4  __attribute__((ext_vector_type(4)));

// async global->LDS, 16B per lane (global_load_lds_dwordx4).
__device__ __forceinline__ void glds16(const void* gp, void* lp) {
  __builtin_amdgcn_global_load_lds(
      (const __attribute__((address_space(1))) void*)gp,
      (__attribute__((address_space(3))) void*)lp, 16, 0, 0);
}

__device__ __forceinline__ float silu_f(float x) {
  return x * __builtin_amdgcn_rcpf(1.0f + __expf(-x));
}

// LDS XOR-swizzle: 16B-chunk k8 within a 64B row is permuted by ((row>>1)&3)
// so fragment reads are 2-way-per-bank-group (free) instead of 8-way.
__device__ __forceinline__ int swz(int k8, int r) { return k8 ^ ((r >> 1) & 3); }

// ---------------- split fp32 -> hi/lo f16 (vectorized) ----------------
__global__ void split_x_k(const float* __restrict__ in, f16* __restrict__ oh,
                          f16* __restrict__ ol, int n) {
  int i = (blockIdx.x * blockDim.x + threadIdx.x) * 4;
  const int stride = gridDim.x * blockDim.x * 4;
  for (; i < n; i += stride) {
    float4 v = *(const float4*)(in + i);
    f16x4 h, l;
    h[0] = (f16)v.x; l[0] = (f16)(v.x - (float)h[0]);
    h[1] = (f16)v.y; l[1] = (f16)(v.y - (float)h[1]);
    h[2] = (f16)v.z; l[2] = (f16)(v.z - (float)h[2]);
    h[3] = (f16)v.w; l[3] = (f16)(v.w - (float)h[3]);
    *(f16x4*)(oh + i) = h;
    *(f16x4*)(ol + i) = l;
  }
}

// ---------------- transpose + split: in[R][C] fp32 -> hi/lo [C][R] f16 ----------------
__global__ void transpose_split_k(const float* __restrict__ in, f16* __restrict__ oh,
                                  f16* __restrict__ ol, int R, int C) {
  __shared__ float tile[32][33];
  const int c0 = blockIdx.x * 32, r0 = blockIdx.y * 32;
  const int tx = threadIdx.x, ty = threadIdx.y; // 32 x 8
  #pragma unroll
  for (int i = 0; i < 4; ++i)
    tile[ty + i*8][tx] = in[(size_t)(r0 + ty + i*8) * C + c0 + tx];
  __syncthreads();
  #pragma unroll
  for (int i = 0; i < 4; ++i) {
    float v = tile[tx][ty + i*8];
    f16 h = (f16)v;
    size_t idx = (size_t)(c0 + ty + i*8) * R + r0 + tx;
    oh[idx] = h;
    ol[idx] = (f16)(v - (float)h);
  }
}

// ---------------- transpose + cast to f16 ----------------
__global__ void transpose_cast_f16_k(const float* __restrict__ in, f16* __restrict__ out, int R, int C) {
  __shared__ float tile[32][33];
  const int c0 = blockIdx.x * 32, r0 = blockIdx.y * 32;
  const int tx = threadIdx.x, ty = threadIdx.y;
  #pragma unroll
  for (int i = 0; i < 4; ++i)
    tile[ty + i*8][tx] = in[(size_t)(r0 + ty + i*8) * C + c0 + tx];
  __syncthreads();
  #pragma unroll
  for (int i = 0; i < 4; ++i)
    out[(size_t)(c0 + ty + i*8) * R + r0 + tx] = (f16)tile[tx][ty + i*8];
}

// ---------------- GEMM1: xproj = silu(x @ W_in + b), pure-f16 hi/lo ----------------
// 512 threads, 8 waves, block tile 128x128, wave tile 64x32. K=1024, N=2048.
// T3-minimum 2-phase: double-buffered LDS, stage(t+1) issued BEFORE compute(t),
// ONE __syncthreads per K-tile. XCD supertile + LDS XOR-swizzle.  [round-4/6 verbatim]
__global__ __launch_bounds__(512) void gemm1_k(const f16* __restrict__ Ah, const f16* __restrict__ Al,
                                               const f16* __restrict__ Bh, const f16* __restrict__ Bl,
                                               const float* __restrict__ bias,
                                               f16* __restrict__ Ch, f16* __restrict__ Cl) {
  const int K = 1024, N = 2048;
  __shared__ f16 sAh[2][4096], sAl[2][4096], sBh[2][4096], sBl[2][4096];  // 64KB

  const int tid = threadIdx.x;
  const int w = tid >> 6, l = tid & 63;
  const int bid = blockIdx.x;              // 0..1023
  const int xcd = bid & 7, loc = bid >> 3; // loc 0..127
  const int mt = xcd * 8 + (loc & 7);      // 0..63
  const int nt = loc >> 3;                 // 0..15
  const int bm = mt * 128, bn = nt * 128;
  const int wm = (w >> 2) * 64, wn = (w & 3) * 32;
  const int lr = l & 15, lq = l >> 4;

  // staging: chunk tid of each tensor; LDS chunk tid holds global chunk (r, swz(k8,r))
  const int r = tid >> 2, k8 = swz(tid & 3, r);
  const f16* pAh = Ah + (size_t)(bm + r) * K + k8 * 8;
  const f16* pAl = Al + (size_t)(bm + r) * K + k8 * 8;
  const f16* pBh = Bh + (size_t)(bn + r) * K + k8 * 8;
  const f16* pBl = Bl + (size_t)(bn + r) * K + k8 * 8;
  const int dst = tid * 8;

  int offA[4], offB[2];
  #pragma unroll
  for (int i = 0; i < 4; ++i) {
    const int row = wm + i*16 + lr;
    offA[i] = row * 32 + swz(lq, row) * 8;
  }
  #pragma unroll
  for (int j = 0; j < 2; ++j) {
    const int row = wn + j*16 + lr;
    offB[j] = row * 32 + swz(lq, row) * 8;
  }

  f32x4 acc[4][2] = {};

  // prologue: stage tile 0 into buf 0
  glds16(pAh, &sAh[0][dst]); glds16(pAl, &sAl[0][dst]);
  glds16(pBh, &sBh[0][dst]); glds16(pBl, &sBl[0][dst]);
  pAh += 32; pAl += 32; pBh += 32; pBl += 32;
  __syncthreads();  // drains vmcnt

  for (int kt = 0; kt < 32; ++kt) {
    const int cur = kt & 1;
    if (kt < 31) {
      const int nxt = cur ^ 1;
      glds16(pAh, &sAh[nxt][dst]); glds16(pAl, &sAl[nxt][dst]);
      glds16(pBh, &sBh[nxt][dst]); glds16(pBl, &sBl[nxt][dst]);
      pAh += 32; pAl += 32; pBh += 32; pBl += 32;
    }
    f16x8 ah[4], al[4], bh[2], bl[2];
    #pragma unroll
    for (int i = 0; i < 4; ++i) {
      ah[i] = *(const f16x8*)(&sAh[cur][0] + offA[i]);
      al[i] = *(const f16x8*)(&sAl[cur][0] + offA[i]);
    }
    #pragma unroll
    for (int j = 0; j < 2; ++j) {
      bh[j] = *(const f16x8*)(&sBh[cur][0] + offB[j]);
      bl[j] = *(const f16x8*)(&sBl[cur][0] + offB[j]);
    }
    __builtin_amdgcn_s_setprio(1);
    #pragma unroll
    for (int i = 0; i < 4; ++i)
      #pragma unroll
      for (int j = 0; j < 2; ++j) {
        acc[i][j] = __builtin_amdgcn_mfma_f32_16x16x32_f16(ah[i], bh[j], acc[i][j], 0, 0, 0);
        acc[i][j] = __builtin_amdgcn_mfma_f32_16x16x32_f16(ah[i], bl[j], acc[i][j], 0, 0, 0);
        acc[i][j] = __builtin_amdgcn_mfma_f32_16x16x32_f16(al[i], bh[j], acc[i][j], 0, 0, 0);
      }
    __builtin_amdgcn_s_setprio(0);
    __syncthreads();  // single barrier: drains prefetch vmcnt + syncs
  }

  // epilogue: C/D layout col = lane&15, row = (lane>>4)*4 + reg
  #pragma unroll
  for (int j = 0; j < 2; ++j) {
    const int col = bn + wn + j*16 + lr;
    const float bv = bias[col];
    #pragma unroll
    for (int i = 0; i < 4; ++i)
      #pragma unroll
      for (int r4 = 0; r4 < 4; ++r4) {
        const int row = bm + wm + i*16 + lq*4 + r4;
        const float s = silu_f(acc[i][j][r4] + bv);
        const f16 h = (f16)s;
        const size_t idx = (size_t)row * N + col;
        Ch[idx] = h;
        Cl[idx] = (f16)(s - (float)h);
      }
  }
}

// ---------------- GEMM2: upd = xproj @ W_state + b -> fp32 ----------------
// 512 threads, 8 waves (4Mx2N), block tile 64x64, wave tile 16x32. K=2048, N=256.
// Same BK=64 two-sub staging/swizzle/LDS as r6, but 8 waves/block ->
// 2 blocks/CU x 8 = 16 waves/CU (2x r6's latency hiding; the r4 lesson).
// 1D grid 512, XCD-grouped: the 4 same-A blocks == bm idx mod 8 -> same XCD L2.
__global__ __launch_bounds__(512) void gemm2s_k(const f16* __restrict__ Ah, const f16* __restrict__ Al,
                                                const f16* __restrict__ Bh, const f16* __restrict__ Bl,
                                                const float* __restrict__ bias,
                                                float* __restrict__ C) {
  const int K = 2048, N = 256;
  // [buf][sub][64 rows x 32 k] per tensor: 4 tensors x 16KB = 64KB
  __shared__ f16 sAh[2][2][2048], sAl[2][2][2048], sBh[2][2][2048], sBl[2][2][2048];

  const int tid = threadIdx.x;
  const int w = tid >> 6, l = tid & 63;
  const int bid = blockIdx.x;           // 0..511
  const int bm = (bid & 127) * 64;
  const int bn = (bid >> 7) * 64;
  const int wm = (w >> 1) * 16, wn = (w & 1) * 32;
  const int lr = l & 15, lq = l >> 4;

  // staging: 2048 chunks per K-step (4 tensors x 2 subs x 256); thread stages
  // chunk (c = tid&255) of all 4 tensors for sub s = tid>>8 (4 glds/thread).
  const int c = tid & 255, s = tid >> 8;
  const int r = c >> 2, k8 = swz(c & 3, r);
  const size_t koff = (size_t)s * 32 + k8 * 8;
  const f16* pAh = Ah + (size_t)(bm + r) * K + koff;
  const f16* pAl = Al + (size_t)(bm + r) * K + koff;
  const f16* pBh = Bh + (size_t)(bn + r) * K + koff;
  const f16* pBl = Bl + (size_t)(bn + r) * K + koff;
  const int dst = c * 8;

  int offA, offB[2];
  {
    const int row = wm + lr;
    offA = row * 32 + swz(lq, row) * 8;
  }
  #pragma unroll
  for (int j = 0; j < 2; ++j) {
    const int row = wn + j*16 + lr;
    offB[j] = row * 32 + swz(lq, row) * 8;
  }

  f32x4 acc[2] = {};

  // prologue: stage K-step 0 into buf 0
  glds16(pAh, &sAh[0][s][dst]); glds16(pAl, &sAl[0][s][dst]);
  glds16(pBh, &sBh[0][s][dst]); glds16(pBl, &sBl[0][s][dst]);
  pAh += 64; pAl += 64; pBh += 64; pBl += 64;
  __syncthreads();

  for (int kt = 0; kt < 32; ++kt) {   // 32 K-steps of 64
    const int cur = kt & 1;
    if (kt < 31) {
      const int nxt = cur ^ 1;
      glds16(pAh, &sAh[nxt][s][dst]); glds16(pAl, &sAl[nxt][s][dst]);
      glds16(pBh, &sBh[nxt][s][dst]); glds16(pBl, &sBl[nxt][s][dst]);
      pAh += 64; pAl += 64; pBh += 64; pBl += 64;
    }
    #pragma unroll
    for (int ss = 0; ss < 2; ++ss) {
      f16x8 ah, al, bh[2], bl[2];
      ah = *(const f16x8*)(&sAh[cur][ss][0] + offA);
      al = *(const f16x8*)(&sAl[cur][ss][0] + offA);
      #pragma unroll
      for (int j = 0; j < 2; ++j) {
        bh[j] = *(const f16x8*)(&sBh[cur][ss][0] + offB[j]);
        bl[j] = *(const f16x8*)(&sBl[cur][ss][0] + offB[j]);
      }
      __builtin_amdgcn_s_setprio(1);
      #pragma unroll
      for (int j = 0; j < 2; ++j) {
        acc[j] = __builtin_amdgcn_mfma_f32_16x16x32_f16(ah, bh[j], acc[j], 0, 0, 0);
        acc[j] = __builtin_amdgcn_mfma_f32_16x16x32_f16(ah, bl[j], acc[j], 0, 0, 0);
        acc[j] = __builtin_amdgcn_mfma_f32_16x16x32_f16(al, bh[j], acc[j], 0, 0, 0);
      }
      __builtin_amdgcn_s_setprio(0);
    }
    __syncthreads();
  }

  #pragma unroll
  for (int j = 0; j < 2; ++j) {
    const int col = bn + wn + j*16 + lr;
    const float bv = bias[col];
    #pragma unroll
    for (int r4 = 0; r4 < 4; ++r4) {
      const int row = bm + wm + lq*4 + r4;
      C[(size_t)row * N + col] = acc[j][r4] + bv;
    }
  }
}

// ---------------- GEMM3: out = states @ W_out + b -> fp32 (single f16) ----------------
// T3-minimum 2-phase double-buffer, one barrier per K-tile.  [round-4/6 verbatim]
__global__ __launch_bounds__(256) void gemm3_k(const f16* __restrict__ A,
                                               const f16* __restrict__ Bt,
                                               const float* __restrict__ bias,
                                               float* __restrict__ C) {
  const int K = 256, N = 1024;
  __shared__ f16 sA[2][4096], sB[2][4096];  // 32KB

  const int tid = threadIdx.x;
  const int w = tid >> 6, l = tid & 63;
  const int bm = blockIdx.y * 128, bn = blockIdx.x * 128;
  const int wm = (w >> 1) * 64, wn = (w & 1) * 64;
  const int lr = l & 15, lq = l >> 4;

  const f16 *pA[2], *pB[2]; int dstc[2];
  #pragma unroll
  for (int p = 0; p < 2; ++p) {
    const int c = p * 256 + tid;
    const int r = c >> 2, k8 = swz(c & 3, r);
    pA[p] = A  + (size_t)(bm + r) * K + k8 * 8;
    pB[p] = Bt + (size_t)(bn + r) * K + k8 * 8;
    dstc[p] = c * 8;
  }

  int offA[4], offB[4];
  #pragma unroll
  for (int i = 0; i < 4; ++i) {
    const int rowA = wm + i*16 + lr;
    const int rowB = wn + i*16 + lr;
    offA[i] = rowA * 32 + swz(lq, rowA) * 8;
    offB[i] = rowB * 32 + swz(lq, rowB) * 8;
  }

  f32x4 acc[4][4] = {};

  glds16(pA[0], &sA[0][dstc[0]]); glds16(pA[1], &sA[0][dstc[1]]);
  glds16(pB[0], &sB[0][dstc[0]]); glds16(pB[1], &sB[0][dstc[1]]);
  pA[0] += 32; pA[1] += 32; pB[0] += 32; pB[1] += 32;
  __syncthreads();

  for (int kt = 0; kt < 8; ++kt) {
    const int cur = kt & 1;
    if (kt < 7) {
      const int nxt = cur ^ 1;
      glds16(pA[0], &sA[nxt][dstc[0]]); glds16(pA[1], &sA[nxt][dstc[1]]);
      glds16(pB[0], &sB[nxt][dstc[0]]); glds16(pB[1], &sB[nxt][dstc[1]]);
      pA[0] += 32; pA[1] += 32; pB[0] += 32; pB[1] += 32;
    }
    f16x8 af[4], bfr[4];
    #pragma unroll
    for (int i = 0; i < 4; ++i) af[i]  = *(const f16x8*)(&sA[cur][0] + offA[i]);
    #pragma unroll
    for (int j = 0; j < 4; ++j) bfr[j] = *(const f16x8*)(&sB[cur][0] + offB[j]);
    __builtin_amdgcn_s_setprio(1);
    #pragma unroll
    for (int i = 0; i < 4; ++i)
      #pragma unroll
      for (int j = 0; j < 4; ++j)
        acc[i][j] = __builtin_amdgcn_mfma_f32_16x16x32_f16(af[i], bfr[j], acc[i][j], 0, 0, 0);
    __builtin_amdgcn_s_setprio(0);
    __syncthreads();
  }

  #pragma unroll
  for (int j = 0; j < 4; ++j) {
    const int col = bn + wn + j*16 + lr;
    const float bv = bias[col];
    #pragma unroll
    for (int i = 0; i < 4; ++i)
      #pragma unroll
      for (int r4 = 0; r4 < 4; ++r4) {
        const int row = bm + wm + i*16 + lq*4 + r4;
        C[(size_t)row * N + col] = acc[i][j][r4] + bv;
      }
  }
}

// ---------------- sequential scan: state = silu(state + u_t), fp32 -> f16 states ----------------
// 32 blocks x 64 threads; 3-buffer rotation = loads issued 32 steps ahead.
#define L2E 1.4426950408889634f
__global__ __launch_bounds__(64) void scan_k(const float* __restrict__ upd,
                                             const float* __restrict__ init,
                                             f16* __restrict__ states) {
  const int b = blockIdx.x >> 2, sq = blockIdx.x & 3;
  const int s = sq * 64 + threadIdx.x;
  const float* u = upd + (size_t)b * SEQ * DSZ + s;
  f16* st = states + (size_t)b * SEQ * DSZ + s;
  float state = init[s];

  float r0[16], r1[16], r2[16], ulog[16];
  #pragma unroll
  for (int i = 0; i < 16; ++i) r0[i] = u[(size_t)i * DSZ];
  #pragma unroll
  for (int i = 0; i < 16; ++i) r1[i] = u[(size_t)(16 + i) * DSZ];
  #pragma unroll
  for (int i = 0; i < 16; ++i) ulog[i] = r0[i] * (-L2E);

  for (int t0 = 0; t0 < SEQ; t0 += 16) {
    // loads for t0+32 (two blocks ahead, off the dependency chain)
    if (t0 + 32 < SEQ) {
      #pragma unroll
      for (int i = 0; i < 16; ++i) r2[i] = u[(size_t)(t0 + 32 + i) * DSZ];
    }
    // pure-register dependent chain
    f16 res[16];
    #pragma unroll
    for (int i = 0; i < 16; ++i) {
      const float e = __builtin_amdgcn_exp2f(__builtin_fmaf(state, -L2E, ulog[i]));
      const float x = state + r0[i];
      state = x * __builtin_amdgcn_rcpf(1.0f + e);
      res[i] = (f16)state;
    }
    // stores (off-chain)
    #pragma unroll
    for (int i = 0; i < 16; ++i) st[(size_t)(t0 + i) * DSZ] = res[i];
    // rotate buffers
    #pragma unroll
    for (int i = 0; i < 16; ++i) { r0[i] = r1[i]; ulog[i] = r1[i] * (-L2E); r1[i] = r2[i]; }
  }
}

extern "C" void kernel_launch(void* const* d_in, const int* in_sizes, int n_in,
                              void* d_out, int out_size, void* d_ws, size_t ws_size,
                              hipStream_t stream) {
  const float* x       = (const float*)d_in[0];
  const float* W_in    = (const float*)d_in[1];
  const float* b_in    = (const float*)d_in[2];
  const float* W_state = (const float*)d_in[3];
  const float* b_state = (const float*)d_in[4];
  const float* W_out   = (const float*)d_in[5];
  const float* b_out   = (const float*)d_in[6];
  const float* init_st = (const float*)d_in[7];
  float* out = (float*)d_out;

  char* ws = (char*)d_ws;
  f16*   xh        = (f16*)(ws + 0);             // 32MB [16384][1024]
  f16*   xl        = (f16*)(ws + 33554432);      // 32MB
  f16*   xproj_h   = (f16*)(ws + 67108864);      // 32MB [8192][2048] (per chunk)
  f16*   xproj_l   = (f16*)(ws + 100663296);     // 32MB
  float* upd       = (float*)(ws + 134217728);   // 16MB [16384][256] fp32
  f16*   states    = (f16*)(ws + 150994944);     // 8MB  [16384][256]
  f16*   w_in_h    = (f16*)(ws + 159383552);     // 4MB  [2048][1024]
  f16*   w_in_l    = (f16*)(ws + 163577856);     // 4MB
  f16*   w_state_h = (f16*)(ws + 167772160);     // 1MB  [256][2048]
  f16*   w_state_l = (f16*)(ws + 168820736);     // 1MB
  f16*   w_out_t   = (f16*)(ws + 169869312);     // 0.5MB [1024][256]  (end = 170,393,600 B)

  // 1) pre-split x, transpose+split weights
  split_x_k<<<4096, 256, 0, stream>>>(x, xh, xl, MROWS * DM);
  dim3 tb(32, 8);
  transpose_split_k<<<dim3(DE/32,  DM/32), tb, 0, stream>>>(W_in,    w_in_h,    w_in_l,    DM,  DE);
  transpose_split_k<<<dim3(DSZ/32, DE/32), tb, 0, stream>>>(W_state, w_state_h, w_state_l, DE,  DSZ);
  transpose_cast_f16_k<<<dim3(DM/32, DSZ/32), tb, 0, stream>>>(W_out, w_out_t, DSZ, DM);

  // 2/3) chunked: xproj = silu(x@W_in+b) -> hi/lo f16; upd = xproj@W_state+b -> fp32
  for (int c = 0; c < 2; ++c) {
    const size_t ro = (size_t)c * MCHUNK;
    gemm1_k<<<1024, 512, 0, stream>>>(
        xh + ro * DM, xl + ro * DM, w_in_h, w_in_l, b_in, xproj_h, xproj_l);
    gemm2s_k<<<512, 512, 0, stream>>>(
        xproj_h, xproj_l, w_state_h, w_state_l, b_state, upd + ro * DSZ);
  }

  // 4) sequential scan (fp32), states as f16
  scan_k<<<BATCH*4, 64, 0, stream>>>(upd, init_st, states);

  // 5) out = states @ W_out + b_out -> fp32
  gemm3_k<<<dim3(DM/128, MROWS/128), 256, 0, stream>>>(states, w_out_t, b_out, out);
}